// Round 8
// baseline (272.719 us; speedup 1.0000x reference)
//
#include <hip/hip_runtime.h>

typedef __bf16 bf16x8 __attribute__((ext_vector_type(8)));
typedef float f32x4 __attribute__((ext_vector_type(4)));

#define HW 9216
#define CCH 256

__device__ __forceinline__ unsigned short f2bf(float f) {
  unsigned u = __float_as_uint(f);
  unsigned r = (u + 0x7FFFu + ((u >> 16) & 1u)) >> 16;
  return (unsigned short)r;
}
__device__ __forceinline__ float bf2f(unsigned short h) {
  return __uint_as_float(((unsigned)h) << 16);
}

// async 16B/lane global->LDS DMA; LDS dst = wave-uniform base, lane l writes base+l*16
__device__ __forceinline__ void async16(const unsigned short* g, unsigned short* l) {
  __builtin_amdgcn_global_load_lds(
      (const __attribute__((address_space(1))) unsigned int*)g,
      (__attribute__((address_space(3))) unsigned int*)l, 16, 0, 0);
}

// y[0..4) += gk * unpack_bf16x4(v)
__device__ __forceinline__ void fma4(float* y, float gk, uint2 v) {
  y[0] += gk * __uint_as_float(v.x << 16);
  y[1] += gk * __uint_as_float(v.x & 0xFFFF0000u);
  y[2] += gk * __uint_as_float(v.y << 16);
  y[3] += gk * __uint_as_float(v.y & 0xFFFF0000u);
}

// ---------- x [n][ci][p] fp32 -> xb [n*9216+p][ci] bf16 ----------
__global__ __launch_bounds__(256) void xpose(const float* __restrict__ x,
                                             unsigned short* __restrict__ xb) {
  __shared__ float tile[64][65];
  int t = threadIdx.x;
  int p0 = blockIdx.x * 64, ci0 = blockIdx.y * 64, n = blockIdx.z;
  int cl = t & 63, q = t >> 6;
#pragma unroll
  for (int i = 0; i < 16; ++i) {
    int cir = q + i * 4;
    tile[cir][cl] = x[((size_t)(n * 256 + ci0 + cir)) * HW + p0 + cl];
  }
  __syncthreads();
#pragma unroll
  for (int i = 0; i < 16; ++i) {
    int pr = q + i * 4;
    xb[((size_t)(n * HW + p0 + pr)) * 256 + ci0 + cl] = f2bf(tile[cl][pr]);
  }
}

// ---------- weight repack ----------
__global__ __launch_bounds__(256) void prep_w(const float* __restrict__ Ws,
                                              const float* __restrict__ Wc,
                                              unsigned short* __restrict__ Wsb,
                                              unsigned short* __restrict__ Wcb) {
  int u = blockIdx.x * 256 + threadIdx.x;
  if (u < 393216) {
    int j = u >> 8, k = u & 255;
    int co = j & 255, b = j >> 8;
    Wsb[u] = f2bf(Ws[(size_t)co * 1536 + b * 256 + k]);
  } else {
    int v = u - 393216;
    if (v < 110592) {
      int co = v / 2304, r = v % 2304;
      int j = r >> 8, ci = r & 255;
      Wcb[v] = (co < 45) ? f2bf(Wc[(size_t)co * 2304 + ci * 9 + j]) : (unsigned short)0;
    }
  }
}

// ---------- gemm_z: async-staged, LDS image = proven [kq][mm] layout ----------
// DMA chunk c (64 uint4): kq = c>>1, mm = (c&1)*64 + lane. Waves 0/1 stage As
// halves 0/1 (4 kq-issues each, one 64B line per lane); waves 2/3 stage Bs.
// Output layout: z[slice][cg32][m][8ch] (channel-blocked for dense accum rows).
__global__ __launch_bounds__(256) void gemm_z(const unsigned short* __restrict__ xb,
                                              const unsigned short* __restrict__ Wsb,
                                              unsigned short* __restrict__ z) {
  __shared__ unsigned short As[4096];  // uint4 idx = kq*128 + mm
  __shared__ unsigned short Bs[4096];
  int t = threadIdx.x;
  int wid = t >> 6, lane = t & 63;
  int m0 = blockIdx.x * 128, c0 = blockIdx.y * 128;
  int wm = (wid >> 1) * 64, wn = (wid & 1) * 64;
  int q = lane >> 4, ln = lane & 15;
  int half = wid & 1;
  const unsigned short* gbase =
      (wid < 2) ? xb + (size_t)(m0 + half * 64 + lane) * 256
                : Wsb + (size_t)(c0 + half * 64 + lane) * 256;
  unsigned short* lbase = (wid < 2) ? As : Bs;
  f32x4 acc[4][4] = {};

  for (int k0 = 0; k0 < 256; k0 += 32) {
#pragma unroll
    for (int kq = 0; kq < 4; ++kq) {
      int c = kq * 2 + half;
      async16(gbase + k0 + kq * 8, lbase + c * 512);
    }
    __syncthreads();
    bf16x8 a[4], b[4];
#pragma unroll
    for (int f = 0; f < 4; ++f) {
      a[f] = ((const bf16x8*)As)[q * 128 + wm + f * 16 + ln];
      b[f] = ((const bf16x8*)Bs)[q * 128 + wn + f * 16 + ln];
    }
#pragma unroll
    for (int fm = 0; fm < 4; ++fm)
#pragma unroll
      for (int fn = 0; fn < 4; ++fn)
        acc[fm][fn] = __builtin_amdgcn_mfma_f32_16x16x32_bf16(a[fm], b[fn], acc[fm][fn], 0, 0, 0);
    __syncthreads();
  }

  int sl = c0 >> 8;
  int cb = c0 & 255;
#pragma unroll
  for (int fm = 0; fm < 4; ++fm) {
    int mrow = m0 + wm + fm * 16 + q * 4;
#pragma unroll
    for (int fn = 0; fn < 4; ++fn) {
      int ch = cb + wn + fn * 16 + ln;
      size_t gb = (size_t)(sl * 32 + (ch >> 3)) * 18432;
      int cw = ch & 7;
#pragma unroll
      for (int r = 0; r < 4; ++r)
        z[(gb + mrow + r) * 8 + cw] = f2bf(acc[fm][fn][r]);
    }
  }
}

// ---------- guidance GEMM ----------
__global__ __launch_bounds__(256) void gemm_g(const unsigned short* __restrict__ xb,
                                              const unsigned short* __restrict__ Wcb,
                                              float* __restrict__ g45) {
  __shared__ unsigned short As[4 * 64 * 8];
  __shared__ unsigned short Bs[4 * 48 * 8];
  int t = threadIdx.x;
  int m0 = blockIdx.x * 64;
  int wid = t >> 6, lane = t & 63;
  int q = lane >> 4, ln = lane & 15;
  int mm = t >> 2, kq = t & 3;
  int m = m0 + mm;
  int nimg = m / HW, p = m % HW;
  int h = p / 96, w = p % 96;
  int mbase = nimg * HW;
  f32x4 acc[3] = {};

  for (int k0 = 0; k0 < 2304; k0 += 32) {
    int j = k0 >> 8;
    int dy = j / 3 - 1, dx = j % 3 - 1;
    int hh = h + dy, ww = w + dx;
    uint4 av = make_uint4(0, 0, 0, 0);
    if ((unsigned)hh < 96u && (unsigned)ww < 96u)
      av = *(const uint4*)(xb + (size_t)(mbase + hh * 96 + ww) * 256 + (k0 & 255) + kq * 8);
    ((uint4*)As)[kq * 64 + mm] = av;
    if (t < 192) {
      int nn = t >> 2, kq2 = t & 3;
      ((uint4*)Bs)[kq2 * 48 + nn] = *(const uint4*)(Wcb + (size_t)nn * 2304 + k0 + kq2 * 8);
    }
    __syncthreads();
    bf16x8 a = ((const bf16x8*)As)[q * 64 + wid * 16 + ln];
#pragma unroll
    for (int fn = 0; fn < 3; ++fn) {
      bf16x8 b = ((const bf16x8*)Bs)[q * 48 + fn * 16 + ln];
      acc[fn] = __builtin_amdgcn_mfma_f32_16x16x32_bf16(a, b, acc[fn], 0, 0, 0);
    }
    __syncthreads();
  }
#pragma unroll
  for (int fn = 0; fn < 3; ++fn) {
    int col = fn * 16 + ln;
    int mrow = m0 + wid * 16 + q * 4;
#pragma unroll
    for (int r = 0; r < 4; ++r)
      g45[(size_t)(mrow + r) * 48 + col] = acc[fn][r];
  }
}

// ---------- softmax -> bf16 col-major gsmb[col][img][p] ----------
__global__ __launch_bounds__(256) void softmax45(const float* __restrict__ g45,
                                                 unsigned short* __restrict__ gsmb) {
  int m = blockIdx.x * 256 + threadIdx.x;
  int img = m / HW, p = m % HW;
  const float* g = g45 + (size_t)m * 48;
  for (int grp = 0; grp < 5; ++grp) {
    float v[9], mx = -1e30f;
#pragma unroll
    for (int k = 0; k < 9; ++k) { v[k] = g[grp * 9 + k]; mx = fmaxf(mx, v[k]); }
    float s = 0.f;
#pragma unroll
    for (int k = 0; k < 9; ++k) { v[k] = __expf(v[k] - mx); s += v[k]; }
    float inv = 1.f / s;
#pragma unroll
    for (int k = 0; k < 9; ++k) {
      int col = grp * 9 + k;
      gsmb[((size_t)(col * 2 + img)) * HW + p] = f2bf(v[k] * inv);
    }
  }
}

// ---------- accum: single pass; block = (row h, img, 8-ch group of 32) ----------
// z layout [slice][cg32][m][8ch]: a staged row is 1536B fully dense.
// 192 threads: px = t>>1, half = t&1 (4 channels via uint2). LDS 33KB -> 4 blk/CU.
__constant__ const int SLs[16] = {0, 1,1,1, 2,2,2, 3,3,3, 4,4,4, 5,5,5};
__constant__ const int DYs[16] = {0, -1,0,1, -6,0,6, -12,0,12, -24,0,24, -36,0,36};

__global__ __launch_bounds__(192) void accum_all(const unsigned short* __restrict__ z,
                                                 const unsigned short* __restrict__ gsmb,
                                                 float* __restrict__ yacc,
                                                 float* __restrict__ stats) {
  __shared__ unsigned short rows[16 * 768];  // [slot][96px][8ch] = 24KB
  __shared__ unsigned short gw[45 * 96];     // [col][px] = 8.4KB
  int t = threadIdx.x;
  int h = blockIdx.x, img = blockIdx.y, cg = blockIdx.z;
  int wid = t >> 6, lane = t & 63;

  // stage z rows: each slot = 1536B = full-wave issue + half-wave issue
  for (int s = wid; s < 16; s += 3) {
    int hr = min(max(h + DYs[s], 0), 95);
    const unsigned short* src =
        z + ((size_t)(SLs[s] * 32 + cg) * 18432 + img * HW + hr * 96) * 8;
    async16(src + lane * 8, &rows[s * 768]);
    if (lane < 32) async16(src + 512 + lane * 8, &rows[s * 768 + 512]);
  }
  // stage weight rows (192B = 12 lanes each)
  for (int c = wid; c < 45; c += 3) {
    const unsigned short* src = gsmb + ((size_t)(c * 2 + img)) * HW + h * 96;
    if (lane < 12) async16(src + lane * 8, &gw[c * 96]);
  }
  __syncthreads();

  int half = t & 1, px = t >> 1;
  bool rv[16];
#pragma unroll
  for (int s = 0; s < 16; ++s) rv[s] = (unsigned)(h + DYs[s]) < 96u;

  float y[4] = {0.f, 0.f, 0.f, 0.f};
  fma4(y, 1.f, *(const uint2*)&rows[px * 8 + half * 4]);  // identity (slot 0)

  const int dil[6] = {0, 1, 6, 12, 24, 36};
#pragma unroll
  for (int b = 1; b <= 5; ++b) {
    const int d = dil[b];
    const int sb = 1 + (b - 1) * 3;
#pragma unroll
    for (int k = 0; k < 9; ++k) {
      const int slot = sb + k / 3;
      const int dx = (k % 3 - 1) * d;
      int wt = px + dx;
      bool valid = rv[slot] && ((unsigned)wt < 96u);
      int widx = valid ? wt : px;
      float gk = valid ? bf2f(gw[((b - 1) * 9 + k) * 96 + px]) : 0.f;
      fma4(y, gk, *(const uint2*)&rows[slot * 768 + widx * 8 + half * 4]);
    }
  }

  size_t ybase = ((size_t)img * HW + h * 96 + px) * 256 + cg * 8 + half * 4;
  *(float4*)(yacc + ybase) = make_float4(y[0], y[1], y[2], y[3]);

  // BN stats: shfl over px (preserve bit0=half), tiny LDS across waves
  float s1[4], s2[4];
#pragma unroll
  for (int j = 0; j < 4; ++j) { s1[j] = y[j]; s2[j] = y[j] * y[j]; }
#pragma unroll
  for (int off = 2; off <= 32; off <<= 1) {
#pragma unroll
    for (int j = 0; j < 4; ++j) {
      s1[j] += __shfl_xor(s1[j], off);
      s2[j] += __shfl_xor(s2[j], off);
    }
  }
  __syncthreads();  // all gw reads done before aliasing
  float* red = (float*)gw;  // [2 stats][3 waves x 2 half][4]
  if (lane < 2) {
#pragma unroll
    for (int j = 0; j < 4; ++j) {
      red[(wid * 2 + lane) * 4 + j] = s1[j];
      red[24 + (wid * 2 + lane) * 4 + j] = s2[j];
    }
  }
  __syncthreads();
  if (t < 16) {
    int stat = t >> 3, i = t & 7;
    int hh = i >> 2, j = i & 3;
    float a = 0.f;
#pragma unroll
    for (int w2 = 0; w2 < 3; ++w2) a += red[stat * 24 + (w2 * 2 + hh) * 4 + j];
    atomicAdd(&stats[stat * 256 + cg * 8 + i], a);
  }
}

// ---------- normalize + affine + transpose ----------
__global__ __launch_bounds__(256) void bn_apply(const float* __restrict__ yacc,
                                                const float* __restrict__ stats,
                                                const float* __restrict__ gamma,
                                                const float* __restrict__ beta,
                                                float* __restrict__ out) {
  __shared__ float tile[64][65];
  int t = threadIdx.x;
  int p0 = blockIdx.x * 64, co0 = blockIdx.y * 64, n = blockIdx.z;
  int cl = t & 63, q = t >> 6;
#pragma unroll
  for (int i = 0; i < 16; ++i) {
    int pr = q + i * 4;
    tile[pr][cl] = yacc[((size_t)n * HW + p0 + pr) * 256 + co0 + cl];
  }
  __syncthreads();
  const float inv_cnt = 1.f / 18432.f;
#pragma unroll
  for (int i = 0; i < 16; ++i) {
    int cr = q + i * 4;
    int c = co0 + cr;
    float mean = stats[c] * inv_cnt;
    float var = stats[256 + c] * inv_cnt - mean * mean;
    float sc = rsqrtf(var + 1e-5f) * gamma[c];
    float sh = beta[c] - mean * sc;
    out[(size_t)(n * 256 + c) * HW + p0 + cl] = tile[cl][cr] * sc + sh;
  }
}

extern "C" void kernel_launch(void* const* d_in, const int* in_sizes, int n_in,
                              void* d_out, int out_size, void* d_ws, size_t ws_size,
                              hipStream_t stream) {
  const float* x = (const float*)d_in[0];
  const float* Wc = (const float*)d_in[1];
  const float* Ws = (const float*)d_in[2];
  const float* gamma = (const float*)d_in[3];
  const float* beta = (const float*)d_in[4];
  float* out = (float*)d_out;

  unsigned short* xb = (unsigned short*)d_ws;   // 4718592 us
  unsigned short* Wsb = xb + 4718592;           // 393216 us
  unsigned short* Wcb = Wsb + 393216;           // 110592 us
  unsigned short* z = Wcb + 110592;             // 28311552 us  [6][32cg][18432][8]
  unsigned short* gsmb = z + 28311552;          // 829440 us    [45][2][9216]
  float* g45 = (float*)(gsmb + 829440);         // 884736 f32
  float* yacc = g45 + 884736;                   // 4718592 f32
  float* stats = yacc + 4718592;                // 512 f32   (total ~91 MB)

  hipMemsetAsync(stats, 0, 512 * sizeof(float), stream);
  xpose<<<dim3(144, 4, 2), 256, 0, stream>>>(x, xb);
  prep_w<<<1968, 256, 0, stream>>>(Ws, Wc, Wsb, Wcb);
  gemm_g<<<288, 256, 0, stream>>>(xb, Wcb, g45);
  softmax45<<<72, 256, 0, stream>>>(g45, gsmb);

  gemm_z<<<dim3(144, 12), 256, 0, stream>>>(xb, Wsb, z);
  accum_all<<<dim3(96, 2, 32), 192, 0, stream>>>(z, gsmb, yacc, stats);

  bn_apply<<<dim3(144, 4, 2), 256, 0, stream>>>(yacc, stats, gamma, beta, out);
}

// Round 10
// 234.129 us; speedup vs baseline: 1.1648x; 1.1648x over previous
//
#include <hip/hip_runtime.h>

typedef __bf16 bf16x8 __attribute__((ext_vector_type(8)));
typedef float f32x4 __attribute__((ext_vector_type(4)));

#define HW 9216
#define ZSTR 176      // padded row stride (40 | 96 | 40)
#define ZSLAB 16896   // 96*176 elems per (sl,ch,img) slab

__device__ __forceinline__ unsigned short f2bf(float f) {
  unsigned u = __float_as_uint(f);
  unsigned r = (u + 0x7FFFu + ((u >> 16) & 1u)) >> 16;
  return (unsigned short)r;
}
__device__ __forceinline__ float bf2f(unsigned short h) {
  return __uint_as_float(((unsigned)h) << 16);
}

__device__ __forceinline__ void async16(const unsigned short* g, unsigned short* l) {
  __builtin_amdgcn_global_load_lds(
      (const __attribute__((address_space(1))) unsigned int*)g,
      (__attribute__((address_space(3))) unsigned int*)l, 16, 0, 0);
}

// y[j] += w[j] * z[O+j], z drawn from the 16-elem window {lo,hi}, O compile-time
template <int O>
__device__ __forceinline__ void tapfma(float* y, uint4 lo, uint4 hi, uint4 wv) {
  const unsigned short* lu = (const unsigned short*)&lo;
  const unsigned short* hu = (const unsigned short*)&hi;
  const unsigned short* wu = (const unsigned short*)&wv;
#pragma unroll
  for (int j = 0; j < 8; ++j) {
    unsigned short zz = (O + j < 8) ? lu[O + j] : hu[O + j - 8];
    y[j] += bf2f(wu[j]) * bf2f(zz);
  }
}

// one 9-tap branch, all offsets compile-time.
// dy-invalid taps: ADDRESS clamped to a valid row (finite data), weight zeroed.
// (R9 bug: unclamped address read past z; garbage decoding to bf16 Inf made 0*Inf=NaN.)
template <int B, int D>
__device__ __forceinline__ void branch9(float* y, const unsigned short* zslab,
                                        const unsigned short* gb, int h, int w0) {
#define TAPK(K, DY, DX)                                                       \
  {                                                                           \
    int hh = h + (DY);                                                        \
    int hc = min(max(hh, 0), 95);                                             \
    const unsigned short* zr = zslab + hc * ZSTR;                             \
    constexpr int O = (40 + (DX)) & 7;                                        \
    int eb = 40 + w0 + (DX)-O;                                                \
    uint4 lo = *(const uint4*)(zr + eb);                                      \
    uint4 hi = *(const uint4*)(zr + eb + 8);                                  \
    uint4 wv = *(const uint4*)(gb + (size_t)(((B - 1) * 9 + (K)) * 2) * HW);  \
    if ((unsigned)hh >= 96u) wv = make_uint4(0u, 0u, 0u, 0u);                 \
    tapfma<O>(y, lo, hi, wv);                                                 \
  }
  TAPK(0, -D, -D) TAPK(1, -D, 0) TAPK(2, -D, D)
  TAPK(3, 0, -D)  TAPK(4, 0, 0)  TAPK(5, 0, D)
  TAPK(6, D, -D)  TAPK(7, D, 0)  TAPK(8, D, D)
#undef TAPK
}

// ---------- init (merged): xpose | weight repack | zero z pads ----------
__global__ __launch_bounds__(256) void init_all(const float* __restrict__ x,
                                                const float* __restrict__ Ws,
                                                const float* __restrict__ Wc,
                                                unsigned short* __restrict__ xb,
                                                unsigned short* __restrict__ Wsb,
                                                unsigned short* __restrict__ Wcb,
                                                unsigned short* __restrict__ z) {
  __shared__ float tile[64][65];
  int id = blockIdx.x;
  int t = threadIdx.x;
  if (id < 1152) {  // xpose: x [n][ci][p] -> xb [n*9216+p][ci]
    int bx = id % 144, by = (id / 144) % 4, n = id / 576;
    int p0 = bx * 64, ci0 = by * 64;
    int cl = t & 63, q = t >> 6;
#pragma unroll
    for (int i = 0; i < 16; ++i) {
      int cir = q + i * 4;
      tile[cir][cl] = x[((size_t)(n * 256 + ci0 + cir)) * HW + p0 + cl];
    }
    __syncthreads();
#pragma unroll
    for (int i = 0; i < 16; ++i) {
      int pr = q + i * 4;
      xb[((size_t)(n * HW + p0 + pr)) * 256 + ci0 + cl] = f2bf(tile[cl][pr]);
    }
  } else if (id < 3120) {  // weight repack
    int u = (id - 1152) * 256 + t;
    if (u < 393216) {
      int j = u >> 8, k = u & 255;
      int co = j & 255, b = j >> 8;
      Wsb[u] = f2bf(Ws[(size_t)co * 1536 + b * 256 + k]);
    } else {
      int v = u - 393216;
      if (v < 110592) {
        int co = v / 2304, r = v % 2304;
        int j = r >> 8, ci = r & 255;
        Wcb[v] = (co < 45) ? f2bf(Wc[(size_t)co * 2304 + ci * 9 + j]) : (unsigned short)0;
      }
    }
  } else {  // zero pads: one thread per padded row, 10 uint4 stores
    int r = (id - 3120) * 256 + t;  // 294912 rows
    unsigned short* base = z + (size_t)r * ZSTR;
    uint4 zero = make_uint4(0u, 0u, 0u, 0u);
#pragma unroll
    for (int i = 0; i < 5; ++i) *(uint4*)(base + i * 8) = zero;
#pragma unroll
    for (int i = 0; i < 5; ++i) *(uint4*)(base + 136 + i * 8) = zero;
  }
}

// ---------- gemms (merged): gemm_z (1728 blocks) | gemm_g (288 blocks) ----------
__global__ __launch_bounds__(256) void gemms(const unsigned short* __restrict__ xb,
                                             const unsigned short* __restrict__ Wsb,
                                             const unsigned short* __restrict__ Wcb,
                                             unsigned short* __restrict__ z,
                                             float* __restrict__ g45) {
  __shared__ unsigned short smem[8192];
  int id = blockIdx.x;
  int t = threadIdx.x;
  int wid = t >> 6, lane = t & 63;
  int q = lane >> 4, ln = lane & 15;

  if (id < 1728) {  // ===== gemm_z: 128x128 tile, async-staged [kq][mm] LDS =====
    unsigned short* As = smem;
    unsigned short* Bs = smem + 4096;
    int m0 = (id % 144) * 128, c0 = (id / 144) * 128;
    int wm = (wid >> 1) * 64, wn = (wid & 1) * 64;
    int half = wid & 1;
    const unsigned short* gbase =
        (wid < 2) ? xb + (size_t)(m0 + half * 64 + lane) * 256
                  : Wsb + (size_t)(c0 + half * 64 + lane) * 256;
    unsigned short* lbase = (wid < 2) ? As : Bs;
    f32x4 acc[4][4] = {};

    for (int k0 = 0; k0 < 256; k0 += 32) {
#pragma unroll
      for (int kq = 0; kq < 4; ++kq) {
        int c = kq * 2 + half;
        async16(gbase + k0 + kq * 8, lbase + c * 512);
      }
      __syncthreads();
      bf16x8 a[4], b[4];
#pragma unroll
      for (int f = 0; f < 4; ++f) {
        a[f] = ((const bf16x8*)As)[q * 128 + wm + f * 16 + ln];
        b[f] = ((const bf16x8*)Bs)[q * 128 + wn + f * 16 + ln];
      }
#pragma unroll
      for (int fm = 0; fm < 4; ++fm)
#pragma unroll
        for (int fn = 0; fn < 4; ++fn)
          acc[fm][fn] = __builtin_amdgcn_mfma_f32_16x16x32_bf16(a[fm], b[fn], acc[fm][fn], 0, 0, 0);
      __syncthreads();
    }

    // epilogue: CHW-padded z; 4 acc regs = 4 consecutive w-pixels -> one 8B store
    int sl = c0 >> 8, cb = c0 & 255;
    int img = m0 / HW;
    int pbase = m0 - img * HW;
#pragma unroll
    for (int fm = 0; fm < 4; ++fm) {
      int p = pbase + wm + fm * 16 + q * 4;
      int hh = p / 96, ww = p % 96;
#pragma unroll
      for (int fn = 0; fn < 4; ++fn) {
        int ch = cb + wn + fn * 16 + ln;
        size_t slab = ((size_t)(sl * 256 + ch) * 2 + img) * ZSLAB;
        unsigned lo = (unsigned)f2bf(acc[fm][fn][0]) | ((unsigned)f2bf(acc[fm][fn][1]) << 16);
        unsigned hi = (unsigned)f2bf(acc[fm][fn][2]) | ((unsigned)f2bf(acc[fm][fn][3]) << 16);
        *(uint2*)(z + slab + hh * ZSTR + 40 + ww) = make_uint2(lo, hi);
      }
    }
  } else {  // ===== gemm_g: 64x48 tile, K=2304 over 9 shifted views =====
    unsigned short* As = smem;            // 2048
    unsigned short* Bs = smem + 2048;     // 1536
    int m0 = (id - 1728) * 64;
    int mm = t >> 2, kq = t & 3;
    int m = m0 + mm;
    int nimg = m / HW, p = m % HW;
    int h = p / 96, w = p % 96;
    int mbase = nimg * HW;
    f32x4 acc[3] = {};

    for (int k0 = 0; k0 < 2304; k0 += 32) {
      int j = k0 >> 8;
      int dy = j / 3 - 1, dx = j % 3 - 1;
      int hh = h + dy, ww = w + dx;
      uint4 av = make_uint4(0, 0, 0, 0);
      if ((unsigned)hh < 96u && (unsigned)ww < 96u)
        av = *(const uint4*)(xb + (size_t)(mbase + hh * 96 + ww) * 256 + (k0 & 255) + kq * 8);
      ((uint4*)As)[kq * 64 + mm] = av;
      if (t < 192) {
        int nn = t >> 2, kq2 = t & 3;
        ((uint4*)Bs)[kq2 * 48 + nn] = *(const uint4*)(Wcb + (size_t)nn * 2304 + k0 + kq2 * 8);
      }
      __syncthreads();
      bf16x8 a = ((const bf16x8*)As)[q * 64 + wid * 16 + ln];
#pragma unroll
      for (int fn = 0; fn < 3; ++fn) {
        bf16x8 b = ((const bf16x8*)Bs)[q * 48 + fn * 16 + ln];
        acc[fn] = __builtin_amdgcn_mfma_f32_16x16x32_bf16(a, b, acc[fn], 0, 0, 0);
      }
      __syncthreads();
    }
#pragma unroll
    for (int fn = 0; fn < 3; ++fn) {
      int col = fn * 16 + ln;
      int mrow = m0 + wid * 16 + q * 4;
#pragma unroll
      for (int r = 0; r < 4; ++r)
        g45[(size_t)(mrow + r) * 48 + col] = acc[fn][r];
    }
  }
}

// ---------- softmax -> bf16 col-major gsmb[col][img][p] ----------
__global__ __launch_bounds__(256) void softmax45(const float* __restrict__ g45,
                                                 unsigned short* __restrict__ gsmb) {
  int m = blockIdx.x * 256 + threadIdx.x;
  int img = m / HW, p = m % HW;
  const float* g = g45 + (size_t)m * 48;
  for (int grp = 0; grp < 5; ++grp) {
    float v[9], mx = -1e30f;
#pragma unroll
    for (int k = 0; k < 9; ++k) { v[k] = g[grp * 9 + k]; mx = fmaxf(mx, v[k]); }
    float s = 0.f;
#pragma unroll
    for (int k = 0; k < 9; ++k) { v[k] = __expf(v[k] - mx); s += v[k]; }
    float inv = 1.f / s;
#pragma unroll
    for (int k = 0; k < 9; ++k) {
      int col = grp * 9 + k;
      gsmb[((size_t)(col * 2 + img)) * HW + p] = f2bf(v[k] * inv);
    }
  }
}

// ---------- accum: pure streaming in CHW; thread = 8 px of one channel ----------
// block 384 thr = 32 h-rows x 12 w-groups; grid (3 h-tiles, 2 img, 256 ch)
__global__ __launch_bounds__(384) void accum_chw(const unsigned short* __restrict__ z,
                                                 const unsigned short* __restrict__ gsmb,
                                                 float* __restrict__ yacc,
                                                 float* __restrict__ stats) {
  __shared__ float red[12];
  int t = threadIdx.x;
  int wq = t % 12, hl = t / 12;
  int h = blockIdx.x * 32 + hl;
  int img = blockIdx.y, ch = blockIdx.z;
  int w0 = wq * 8;
  int p0 = h * 96 + w0;
  const unsigned short* gb = gsmb + (size_t)img * HW + p0;

  float y[8] = {0.f, 0.f, 0.f, 0.f, 0.f, 0.f, 0.f, 0.f};
  // identity (slice 0): aligned single load, weight 1
  {
    const unsigned short* zs = z + ((size_t)(ch * 2 + img)) * ZSLAB;
    uint4 v = *(const uint4*)(zs + h * ZSTR + 40 + w0);
    const unsigned short* u = (const unsigned short*)&v;
#pragma unroll
    for (int j = 0; j < 8; ++j) y[j] += bf2f(u[j]);
  }
  size_t chslab = (size_t)(ch * 2 + img) * ZSLAB;
  branch9<1, 1>(y, z + (size_t)(1 * 512) * ZSLAB + chslab, gb, h, w0);
  branch9<2, 6>(y, z + (size_t)(2 * 512) * ZSLAB + chslab, gb, h, w0);
  branch9<3, 12>(y, z + (size_t)(3 * 512) * ZSLAB + chslab, gb, h, w0);
  branch9<4, 24>(y, z + (size_t)(4 * 512) * ZSLAB + chslab, gb, h, w0);
  branch9<5, 36>(y, z + (size_t)(5 * 512) * ZSLAB + chslab, gb, h, w0);

  size_t ybase = ((size_t)(img * 256 + ch)) * HW + p0;
  *(float4*)(yacc + ybase) = make_float4(y[0], y[1], y[2], y[3]);
  *(float4*)(yacc + ybase + 4) = make_float4(y[4], y[5], y[6], y[7]);

  // BN stats: whole block is one channel -> shfl + tiny LDS + 2 atomics
  float s1 = 0.f, s2 = 0.f;
#pragma unroll
  for (int j = 0; j < 8; ++j) { s1 += y[j]; s2 += y[j] * y[j]; }
#pragma unroll
  for (int off = 1; off <= 32; off <<= 1) {
    s1 += __shfl_xor(s1, off);
    s2 += __shfl_xor(s2, off);
  }
  int wid = t >> 6, lane = t & 63;
  if (lane == 0) { red[wid] = s1; red[6 + wid] = s2; }
  __syncthreads();
  if (t == 0) {
    float a = red[0] + red[1] + red[2] + red[3] + red[4] + red[5];
    atomicAdd(&stats[ch], a);
  } else if (t == 64) {
    float b = red[6] + red[7] + red[8] + red[9] + red[10] + red[11];
    atomicAdd(&stats[256 + ch], b);
  }
}

// ---------- bn: elementwise on CHW (no transpose needed) ----------
__global__ __launch_bounds__(256) void bn_apply(const float* __restrict__ yacc,
                                                const float* __restrict__ stats,
                                                const float* __restrict__ gamma,
                                                const float* __restrict__ beta,
                                                float* __restrict__ out) {
  int q = blockIdx.x * 256 + threadIdx.x;  // quad index
  int ch = (q / 2304) & 255;
  const float inv_cnt = 1.f / 18432.f;
  float mean = stats[ch] * inv_cnt;
  float var = stats[256 + ch] * inv_cnt - mean * mean;
  float sc = rsqrtf(var + 1e-5f) * gamma[ch];
  float sh = beta[ch] - mean * sc;
  float4 v = *(const float4*)(yacc + (size_t)q * 4);
  float4 o = make_float4(v.x * sc + sh, v.y * sc + sh, v.z * sc + sh, v.w * sc + sh);
  *(float4*)(out + (size_t)q * 4) = o;
}

extern "C" void kernel_launch(void* const* d_in, const int* in_sizes, int n_in,
                              void* d_out, int out_size, void* d_ws, size_t ws_size,
                              hipStream_t stream) {
  const float* x = (const float*)d_in[0];
  const float* Wc = (const float*)d_in[1];
  const float* Ws = (const float*)d_in[2];
  const float* gamma = (const float*)d_in[3];
  const float* beta = (const float*)d_in[4];
  float* out = (float*)d_out;

  unsigned short* xb = (unsigned short*)d_ws;   // 4718592 us
  unsigned short* Wsb = xb + 4718592;           // 393216 us
  unsigned short* Wcb = Wsb + 393216;           // 110592 us
  unsigned short* gsmb = Wcb + 110592;          // 829440 us   [45col][2img][9216]
  float* g45 = (float*)(gsmb + 829440);         // 884736 f32
  unsigned short* z = (unsigned short*)(g45 + 884736);  // 51904512 us [6][256][2][96][176]
  float* yacc = (float*)(z + 51904512);         // 4718592 f32 [img][ch][p]
  float* stats = yacc + 4718592;                // 512 f32   total ~132 MB

  hipMemsetAsync(stats, 0, 512 * sizeof(float), stream);
  init_all<<<4272, 256, 0, stream>>>(x, Ws, Wc, xb, Wsb, Wcb, z);
  gemms<<<2016, 256, 0, stream>>>(xb, Wsb, Wcb, z, g45);
  softmax45<<<72, 256, 0, stream>>>(g45, gsmb);
  accum_chw<<<dim3(3, 2, 256), 384, 0, stream>>>(z, gsmb, yacc, stats);
  bn_apply<<<4608, 256, 0, stream>>>(yacc, stats, gamma, beta, out);
}

// Round 11
// 207.370 us; speedup vs baseline: 1.3151x; 1.1290x over previous
//
#include <hip/hip_runtime.h>

typedef __bf16 bf16x8 __attribute__((ext_vector_type(8)));
typedef float f32x4 __attribute__((ext_vector_type(4)));

#define HW 9216
#define ZSTR 176      // padded row stride (40 | 96 | 40)
#define ZSLAB 16896   // 96*176 elems per (sl,ch,img) slab

__device__ __forceinline__ unsigned short f2bf(float f) {
  unsigned u = __float_as_uint(f);
  unsigned r = (u + 0x7FFFu + ((u >> 16) & 1u)) >> 16;
  return (unsigned short)r;
}
__device__ __forceinline__ float bf2f(unsigned short h) {
  return __uint_as_float(((unsigned)h) << 16);
}

__device__ __forceinline__ void async16(const unsigned short* g, unsigned short* l) {
  __builtin_amdgcn_global_load_lds(
      (const __attribute__((address_space(1))) unsigned int*)g,
      (__attribute__((address_space(3))) unsigned int*)l, 16, 0, 0);
}

// y[j] += w[j] * z[O+j], z drawn from the 16-elem window {lo,hi}, O compile-time
template <int O>
__device__ __forceinline__ void tapfma(float* y, uint4 lo, uint4 hi, uint4 wv) {
  const unsigned short* lu = (const unsigned short*)&lo;
  const unsigned short* hu = (const unsigned short*)&hi;
  const unsigned short* wu = (const unsigned short*)&wv;
#pragma unroll
  for (int j = 0; j < 8; ++j) {
    unsigned short zz = (O + j < 8) ? lu[O + j] : hu[O + j - 8];
    y[j] += bf2f(wu[j]) * bf2f(zz);
  }
}

// one 9-tap branch; dy-invalid taps: address clamped to valid row, weight zeroed
template <int B, int D>
__device__ __forceinline__ void branch9(float* y, const unsigned short* zslab,
                                        const unsigned short* gb, int h, int w0) {
#define TAPK(K, DY, DX)                                                       \
  {                                                                           \
    int hh = h + (DY);                                                        \
    int hc = min(max(hh, 0), 95);                                             \
    const unsigned short* zr = zslab + hc * ZSTR;                             \
    constexpr int O = (40 + (DX)) & 7;                                        \
    int eb = 40 + w0 + (DX)-O;                                                \
    uint4 lo = *(const uint4*)(zr + eb);                                      \
    uint4 hi = *(const uint4*)(zr + eb + 8);                                  \
    uint4 wv = *(const uint4*)(gb + (size_t)(((B - 1) * 9 + (K)) * 2) * HW);  \
    if ((unsigned)hh >= 96u) wv = make_uint4(0u, 0u, 0u, 0u);                 \
    tapfma<O>(y, lo, hi, wv);                                                 \
  }
  TAPK(0, -D, -D) TAPK(1, -D, 0) TAPK(2, -D, D)
  TAPK(3, 0, -D)  TAPK(4, 0, 0)  TAPK(5, 0, D)
  TAPK(6, D, -D)  TAPK(7, D, 0)  TAPK(8, D, D)
#undef TAPK
}

// ---------- init (merged): xpose | weight repack | zero z pads ----------
__global__ __launch_bounds__(256) void init_all(const float* __restrict__ x,
                                                const float* __restrict__ Ws,
                                                const float* __restrict__ Wc,
                                                unsigned short* __restrict__ xb,
                                                unsigned short* __restrict__ Wsb,
                                                unsigned short* __restrict__ Wcb,
                                                unsigned short* __restrict__ z) {
  __shared__ float tile[64][65];
  int id = blockIdx.x;
  int t = threadIdx.x;
  if (id < 1152) {  // xpose
    int bx = id % 144, by = (id / 144) % 4, n = id / 576;
    int p0 = bx * 64, ci0 = by * 64;
    int cl = t & 63, q = t >> 6;
#pragma unroll
    for (int i = 0; i < 16; ++i) {
      int cir = q + i * 4;
      tile[cir][cl] = x[((size_t)(n * 256 + ci0 + cir)) * HW + p0 + cl];
    }
    __syncthreads();
#pragma unroll
    for (int i = 0; i < 16; ++i) {
      int pr = q + i * 4;
      xb[((size_t)(n * HW + p0 + pr)) * 256 + ci0 + cl] = f2bf(tile[cl][pr]);
    }
  } else if (id < 3120) {  // weight repack
    int u = (id - 1152) * 256 + t;
    if (u < 393216) {
      int j = u >> 8, k = u & 255;
      int co = j & 255, b = j >> 8;
      Wsb[u] = f2bf(Ws[(size_t)co * 1536 + b * 256 + k]);
    } else {
      int v = u - 393216;
      if (v < 110592) {
        int co = v / 2304, r = v % 2304;
        int j = r >> 8, ci = r & 255;
        Wcb[v] = (co < 45) ? f2bf(Wc[(size_t)co * 2304 + ci * 9 + j]) : (unsigned short)0;
      }
    }
  } else {  // zero pads
    int r = (id - 3120) * 256 + t;
    unsigned short* base = z + (size_t)r * ZSTR;
    uint4 zero = make_uint4(0u, 0u, 0u, 0u);
#pragma unroll
    for (int i = 0; i < 5; ++i) *(uint4*)(base + i * 8) = zero;
#pragma unroll
    for (int i = 0; i < 5; ++i) *(uint4*)(base + 136 + i * 8) = zero;
  }
}

// ---------- gemms: gemm_g first (288 blocks, long critical path) | gemm_z ----------
__global__ __launch_bounds__(256) void gemms(const unsigned short* __restrict__ xb,
                                             const unsigned short* __restrict__ Wsb,
                                             const unsigned short* __restrict__ Wcb,
                                             unsigned short* __restrict__ z,
                                             unsigned short* __restrict__ gsmb) {
  __shared__ unsigned short smem[16384];  // 32KB
  int id = blockIdx.x;
  int t = threadIdx.x;
  int wid = t >> 6, lane = t & 63;
  int q = lane >> 4, ln = lane & 15;

  if (id < 288) {
    // ===== gemm_g: BM=64 BN=48 BK=64 (36 steps), reg-prefetch, fused softmax =====
    unsigned short* As = smem;          // 8 kq x 64 mm x uint4 = 8KB
    unsigned short* Bs = smem + 4096;   // 8 kq x 48 nn x uint4 = 6KB
    int m0 = id * 64;
    int mm = t >> 2, kq = t & 3;
    int m = m0 + mm;
    int img = m / HW, p = m % HW;
    int h = p / 96, w = p % 96;
    int mbase = img * HW;
    int nn = t >> 2;  // for Bs (t<192)
    f32x4 acc[3] = {};
    uint4 aA0, aA1, aB0, aB1;

    // prefetch step 0
    {
      int hh = h - 1, ww = w - 1;  // j=0 -> dy=-1,dx=-1
      bool valid = ((unsigned)hh < 96u) & ((unsigned)ww < 96u);
      const unsigned short* pa = xb + (size_t)(mbase + hh * 96 + ww) * 256 + kq * 8;
      aA0 = valid ? *(const uint4*)pa : make_uint4(0, 0, 0, 0);
      aA1 = valid ? *(const uint4*)(pa + 32) : make_uint4(0, 0, 0, 0);
      if (t < 192) {
        const unsigned short* pb = Wcb + (size_t)nn * 2304 + kq * 8;
        aB0 = *(const uint4*)pb;
        aB1 = *(const uint4*)(pb + 32);
      }
    }

    for (int s = 0; s < 36; ++s) {
      ((uint4*)As)[kq * 64 + mm] = aA0;
      ((uint4*)As)[(kq + 4) * 64 + mm] = aA1;
      if (t < 192) {
        ((uint4*)Bs)[kq * 48 + nn] = aB0;
        ((uint4*)Bs)[(kq + 4) * 48 + nn] = aB1;
      }
      __syncthreads();
      if (s + 1 < 36) {  // prefetch next step; consumed next iteration
        int s1 = s + 1;
        int j = s1 >> 2;
        int hh = h + j / 3 - 1, ww = w + j % 3 - 1;
        bool valid = ((unsigned)hh < 96u) & ((unsigned)ww < 96u);
        const unsigned short* pa =
            xb + (size_t)(mbase + hh * 96 + ww) * 256 + (s1 & 3) * 64 + kq * 8;
        aA0 = valid ? *(const uint4*)pa : make_uint4(0, 0, 0, 0);
        aA1 = valid ? *(const uint4*)(pa + 32) : make_uint4(0, 0, 0, 0);
        if (t < 192) {
          const unsigned short* pb = Wcb + (size_t)nn * 2304 + s1 * 64 + kq * 8;
          aB0 = *(const uint4*)pb;
          aB1 = *(const uint4*)(pb + 32);
        }
      }
#pragma unroll
      for (int kk = 0; kk < 2; ++kk) {
        bf16x8 a = ((const bf16x8*)As)[(kk * 4 + q) * 64 + wid * 16 + ln];
#pragma unroll
        for (int fn = 0; fn < 3; ++fn) {
          bf16x8 b = ((const bf16x8*)Bs)[(kk * 4 + q) * 48 + fn * 16 + ln];
          acc[fn] = __builtin_amdgcn_mfma_f32_16x16x32_bf16(a, b, acc[fn], 0, 0, 0);
        }
      }
      __syncthreads();
    }

    // fused softmax epilogue: acc -> LDS f32 [64px][49], then 64 threads softmax
    float* LDSf = (float*)smem;  // 64*49*4 = 12544B
#pragma unroll
    for (int fn = 0; fn < 3; ++fn)
#pragma unroll
      for (int r = 0; r < 4; ++r)
        LDSf[(wid * 16 + q * 4 + r) * 49 + fn * 16 + ln] = acc[fn][r];
    __syncthreads();
    if (t < 64) {
      const float* row = LDSf + t * 49;
      int mg = m0 + t;
      int img2 = mg / HW, p2 = mg - img2 * HW;
      for (int grp = 0; grp < 5; ++grp) {
        float v[9], mx = -1e30f;
#pragma unroll
        for (int k = 0; k < 9; ++k) { v[k] = row[grp * 9 + k]; mx = fmaxf(mx, v[k]); }
        float sum = 0.f;
#pragma unroll
        for (int k = 0; k < 9; ++k) { v[k] = __expf(v[k] - mx); sum += v[k]; }
        float inv = 1.f / sum;
#pragma unroll
        for (int k = 0; k < 9; ++k) {
          int col = grp * 9 + k;
          gsmb[((size_t)(col * 2 + img2)) * HW + p2] = f2bf(v[k] * inv);
        }
      }
    }
  } else {
    // ===== gemm_z: 128x128, K=256, double-buffered async DMA staging =====
    int zid = id - 288;
    int m0 = (zid % 144) * 128, c0 = (zid / 144) * 128;
    int wm = (wid >> 1) * 64, wn = (wid & 1) * 64;
    int half = wid & 1;
    const unsigned short* gbase =
        (wid < 2) ? xb + (size_t)(m0 + half * 64 + lane) * 256
                  : Wsb + (size_t)(c0 + half * 64 + lane) * 256;
    // buffers: As0 @0, As1 @4096, Bs0 @8192, Bs1 @12288 (shorts)
    unsigned short* lbase0 = (wid < 2) ? smem : smem + 8192;
    f32x4 acc[4][4] = {};

    // stage step 0 into buffer 0
#pragma unroll
    for (int kq = 0; kq < 4; ++kq)
      async16(gbase + kq * 8, lbase0 + (kq * 2 + half) * 512);
    __syncthreads();

    for (int s = 0; s < 8; ++s) {
      int cur = s & 1, nxt = cur ^ 1;
      if (s < 7) {  // issue next-step DMA; drained by end-of-iter barrier
        int k0 = (s + 1) * 32;
#pragma unroll
        for (int kq = 0; kq < 4; ++kq)
          async16(gbase + k0 + kq * 8, lbase0 + nxt * 4096 + (kq * 2 + half) * 512);
      }
      const unsigned short* Asc = smem + cur * 4096;
      const unsigned short* Bsc = smem + 8192 + cur * 4096;
      bf16x8 a[4], b[4];
#pragma unroll
      for (int f = 0; f < 4; ++f) {
        a[f] = ((const bf16x8*)Asc)[q * 128 + wm + f * 16 + ln];
        b[f] = ((const bf16x8*)Bsc)[q * 128 + wn + f * 16 + ln];
      }
#pragma unroll
      for (int fm = 0; fm < 4; ++fm)
#pragma unroll
        for (int fn = 0; fn < 4; ++fn)
          acc[fm][fn] = __builtin_amdgcn_mfma_f32_16x16x32_bf16(a[fm], b[fn], acc[fm][fn], 0, 0, 0);
      __syncthreads();
    }

    // epilogue: CHW-padded z; 4 consecutive w-px -> one 8B store (L2 merges lines)
    int sl = c0 >> 8, cb = c0 & 255;
    int img = m0 / HW;
    int pbase = m0 - img * HW;
#pragma unroll
    for (int fm = 0; fm < 4; ++fm) {
      int p = pbase + wm + fm * 16 + q * 4;
      int hh = p / 96, ww = p % 96;
#pragma unroll
      for (int fn = 0; fn < 4; ++fn) {
        int ch = cb + wn + fn * 16 + ln;
        size_t slab = ((size_t)(sl * 256 + ch) * 2 + img) * ZSLAB;
        unsigned lo = (unsigned)f2bf(acc[fm][fn][0]) | ((unsigned)f2bf(acc[fm][fn][1]) << 16);
        unsigned hi = (unsigned)f2bf(acc[fm][fn][2]) | ((unsigned)f2bf(acc[fm][fn][3]) << 16);
        *(uint2*)(z + slab + hh * ZSTR + 40 + ww) = make_uint2(lo, hi);
      }
    }
  }
}

// ---------- accum: pure streaming in CHW ----------
__global__ __launch_bounds__(384) void accum_chw(const unsigned short* __restrict__ z,
                                                 const unsigned short* __restrict__ gsmb,
                                                 float* __restrict__ yacc,
                                                 float* __restrict__ stats) {
  __shared__ float red[12];
  int t = threadIdx.x;
  int wq = t % 12, hl = t / 12;
  int h = blockIdx.x * 32 + hl;
  int img = blockIdx.y, ch = blockIdx.z;
  int w0 = wq * 8;
  int p0 = h * 96 + w0;
  const unsigned short* gb = gsmb + (size_t)img * HW + p0;

  float y[8] = {0.f, 0.f, 0.f, 0.f, 0.f, 0.f, 0.f, 0.f};
  {
    const unsigned short* zs = z + ((size_t)(ch * 2 + img)) * ZSLAB;
    uint4 v = *(const uint4*)(zs + h * ZSTR + 40 + w0);
    const unsigned short* u = (const unsigned short*)&v;
#pragma unroll
    for (int j = 0; j < 8; ++j) y[j] += bf2f(u[j]);
  }
  size_t chslab = (size_t)(ch * 2 + img) * ZSLAB;
  branch9<1, 1>(y, z + (size_t)(1 * 512) * ZSLAB + chslab, gb, h, w0);
  branch9<2, 6>(y, z + (size_t)(2 * 512) * ZSLAB + chslab, gb, h, w0);
  branch9<3, 12>(y, z + (size_t)(3 * 512) * ZSLAB + chslab, gb, h, w0);
  branch9<4, 24>(y, z + (size_t)(4 * 512) * ZSLAB + chslab, gb, h, w0);
  branch9<5, 36>(y, z + (size_t)(5 * 512) * ZSLAB + chslab, gb, h, w0);

  size_t ybase = ((size_t)(img * 256 + ch)) * HW + p0;
  *(float4*)(yacc + ybase) = make_float4(y[0], y[1], y[2], y[3]);
  *(float4*)(yacc + ybase + 4) = make_float4(y[4], y[5], y[6], y[7]);

  float s1 = 0.f, s2 = 0.f;
#pragma unroll
  for (int j = 0; j < 8; ++j) { s1 += y[j]; s2 += y[j] * y[j]; }
#pragma unroll
  for (int off = 1; off <= 32; off <<= 1) {
    s1 += __shfl_xor(s1, off);
    s2 += __shfl_xor(s2, off);
  }
  int wid = t >> 6, lane = t & 63;
  if (lane == 0) { red[wid] = s1; red[6 + wid] = s2; }
  __syncthreads();
  if (t == 0) {
    float a = red[0] + red[1] + red[2] + red[3] + red[4] + red[5];
    atomicAdd(&stats[ch], a);
  } else if (t == 64) {
    float b = red[6] + red[7] + red[8] + red[9] + red[10] + red[11];
    atomicAdd(&stats[256 + ch], b);
  }
}

// ---------- bn: elementwise on CHW ----------
__global__ __launch_bounds__(256) void bn_apply(const float* __restrict__ yacc,
                                                const float* __restrict__ stats,
                                                const float* __restrict__ gamma,
                                                const float* __restrict__ beta,
                                                float* __restrict__ out) {
  int q = blockIdx.x * 256 + threadIdx.x;
  int ch = (q / 2304) & 255;
  const float inv_cnt = 1.f / 18432.f;
  float mean = stats[ch] * inv_cnt;
  float var = stats[256 + ch] * inv_cnt - mean * mean;
  float sc = rsqrtf(var + 1e-5f) * gamma[ch];
  float sh = beta[ch] - mean * sc;
  float4 v = *(const float4*)(yacc + (size_t)q * 4);
  float4 o = make_float4(v.x * sc + sh, v.y * sc + sh, v.z * sc + sh, v.w * sc + sh);
  *(float4*)(out + (size_t)q * 4) = o;
}

extern "C" void kernel_launch(void* const* d_in, const int* in_sizes, int n_in,
                              void* d_out, int out_size, void* d_ws, size_t ws_size,
                              hipStream_t stream) {
  const float* x = (const float*)d_in[0];
  const float* Wc = (const float*)d_in[1];
  const float* Ws = (const float*)d_in[2];
  const float* gamma = (const float*)d_in[3];
  const float* beta = (const float*)d_in[4];
  float* out = (float*)d_out;

  unsigned short* xb = (unsigned short*)d_ws;   // 4718592 us
  unsigned short* Wsb = xb + 4718592;           // 393216 us
  unsigned short* Wcb = Wsb + 393216;           // 110592 us
  unsigned short* gsmb = Wcb + 110592;          // 829440 us   [45col][2img][9216]
  unsigned short* z = gsmb + 829440;            // 51904512 us [6][256][2][96][176]
  float* yacc = (float*)(z + 51904512);         // 4718592 f32 [img][ch][p]
  float* stats = yacc + 4718592;                // 512 f32

  hipMemsetAsync(stats, 0, 512 * sizeof(float), stream);
  init_all<<<4272, 256, 0, stream>>>(x, Ws, Wc, xb, Wsb, Wcb, z);
  gemms<<<2016, 256, 0, stream>>>(xb, Wsb, Wcb, z, gsmb);
  accum_chw<<<dim3(3, 2, 256), 384, 0, stream>>>(z, gsmb, yacc, stats);
  bn_apply<<<4608, 256, 0, stream>>>(yacc, stats, gamma, beta, out);
}